// Round 5
// baseline (315.369 us; speedup 1.0000x reference)
//
#include <hip/hip_runtime.h>
#include <math.h>

#define Bb 4
#define Nn 2048
#define Ee 768
#define Hh 12
#define Dd 64
#define RD 32
#define EPSf 1e-6f
#define NEG_BIG -3.0e38f
#define PIT 72   // bf16 pitch for 64-wide LDS tiles (16B-aligned rows, pad 8)
#define NTQ 32   // number of 64-row q tiles per (b,h)

typedef __attribute__((ext_vector_type(8))) short short8;
typedef __attribute__((ext_vector_type(4))) float f32x4;

__device__ inline float wave_reduce_sum(float v) {
    #pragma unroll
    for (int m = 1; m < 64; m <<= 1) v += __shfl_xor(v, m, 64);
    return v;
}

// round-to-nearest-even fp32 -> bf16 bits
__device__ inline unsigned f2bf(float x) {
    union { float f; unsigned u; } c; c.f = x;
    unsigned r = c.u + 0x7FFFu + ((c.u >> 16) & 1u);
    return r >> 16;
}

// fp64-accurate rope/xpos tables: idx = n*16 + i
__global__ void tab_kernel(float* __restrict__ ctab, float* __restrict__ stab,
                           float* __restrict__ sctab) {
    int idx = blockIdx.x * 256 + threadIdx.x;
    if (idx >= Nn * 16) return;
    int n = idx >> 4, i = idx & 15;
    double inv_freq = pow(10000.0, -(double)(2 * i) / (double)RD);
    double ang = (double)n * inv_freq;
    ctab[idx] = (float)cos(ang);
    stab[idx] = (float)sin(ang);
    double base = (2.0 * (double)i + 0.4 * (double)RD) / (1.4 * (double)RD);
    double pw = ((double)n - (double)(Nn / 2)) / 512.0;
    sctab[idx] = (float)pow(base, pw);
}

// One wave per (b,h,n): RMS-norm + xPos rope; writes bf16 (B,H,N,D).
// 0.125/sqrtD AND log2(e) folded into q so softmax can use exp2.
__global__ __launch_bounds__(256) void prep_kernel(
    const float* __restrict__ q, const float* __restrict__ k,
    const float* __restrict__ qscale, const float* __restrict__ kscale,
    const float* __restrict__ ctab, const float* __restrict__ stab,
    const float* __restrict__ sctab,
    unsigned short* __restrict__ qn, unsigned short* __restrict__ kn)
{
    int wave = blockIdx.x * 4 + (threadIdx.x >> 6);
    int lane = threadIdx.x & 63;
    int n  = wave % Nn;
    int bh = wave / Nn;
    int h  = bh % Hh;
    int b  = bh / Hh;
    int gidx = (b * Nn + n) * Ee + h * Dd + lane;
    float xq = q[gidx], xk = k[gidx];
    float msq = wave_reduce_sum(xq * xq) * (1.0f / 64.0f);
    float msk = wave_reduce_sum(xk * xk) * (1.0f / 64.0f);
    float xqn = xq * qscale[lane] * rsqrtf(msq + EPSf);
    float xkn = xk * kscale[lane] * rsqrtf(msk + EPSf);
    float pq = __shfl_xor(xqn, 1, 64);
    float pk = __shfl_xor(xkn, 1, 64);
    float oq = xqn, ok = xkn;
    if (lane < RD) {
        int i = lane >> 1;
        float c  = ctab[n * 16 + i];
        float s  = stab[n * 16 + i];
        float sc = sctab[n * 16 + i];
        float rq = (lane & 1) ? pq : -pq;
        float rk = (lane & 1) ? pk : -pk;
        oq = (xqn * c + rq * s) * sc;
        ok = (xkn * c + rk * s) / sc;
    }
    oq *= 0.125f * 1.44269504088896f;   // 1/sqrt(D) * log2(e)
    size_t oidx = (size_t)bh * (Nn * Dd) + (size_t)n * Dd + lane;
    qn[oidx] = (unsigned short)f2bf(oq);
    kn[oidx] = (unsigned short)f2bf(ok);
}

// Transpose V: (B,N,E) fp32 -> (B,H,D,N) bf16
__global__ __launch_bounds__(256) void vt_kernel(
    const float* __restrict__ v, unsigned short* __restrict__ vt)
{
    __shared__ float Vl[64 * 65];
    int t = threadIdx.x;
    int bh = blockIdx.x >> 5;
    int n0 = (blockIdx.x & 31) * 64;
    int b = bh / Hh, h = bh % Hh;
    const float4* v4 = (const float4*)v;
    #pragma unroll
    for (int c = 0; c < 4; ++c) {
        int idx = t + c * 256;
        int n = idx >> 4, d4 = idx & 15;
        float4 vv = v4[(size_t)(b * Nn + n0 + n) * (Ee / 4) + h * 16 + d4];
        int la = n * 65 + d4 * 4;
        Vl[la] = vv.x; Vl[la + 1] = vv.y; Vl[la + 2] = vv.z; Vl[la + 3] = vv.w;
    }
    __syncthreads();
    #pragma unroll
    for (int c = 0; c < 16; ++c) {
        int linear = t + c * 256;
        int d = linear >> 6, n = linear & 63;
        vt[((size_t)bh * Dd + d) * Nn + n0 + n] = (unsigned short)f2bf(Vl[n * 65 + d]);
    }
}

// W (E,E) fp32 -> bf16
__global__ __launch_bounds__(256) void wcvt_kernel(
    const float* __restrict__ w, unsigned short* __restrict__ wb)
{
    int idx = blockIdx.x * 256 + threadIdx.x;
    float4 v = ((const float4*)w)[idx];
    uint2 uu;
    uu.x = f2bf(v.x) | (f2bf(v.y) << 16);
    uu.y = f2bf(v.z) | (f2bf(v.w) << 16);
    *(uint2*)(wb + (size_t)idx * 4) = uu;
}

// MFMA flash attention (causal), balanced + pipelined.
// Block x handles q-tile x then (NTQ-1-x): every block does 33 tile-steps.
// Double-buffered K/V LDS, ONE barrier per tile; next tile's global loads
// issued right after the barrier, LDS-stored after compute.
__global__ __launch_bounds__(256) void attn_kernel(
    const unsigned short* __restrict__ qn, const unsigned short* __restrict__ kn,
    const unsigned short* __restrict__ vt, unsigned short* __restrict__ y)
{
    __shared__ __align__(16) unsigned short Kb[2][64 * PIT];
    __shared__ __align__(16) unsigned short Vb[2][64 * PIT];
    __shared__ __align__(16) unsigned short Pl[4 * 16 * PIT];
    int t = threadIdx.x;
    int w = t >> 6, lane = t & 63;
    int quad = lane >> 4, col = lane & 15;
    int bh = blockIdx.y;
    int b = bh / Hh, h = bh % Hh;
    const unsigned short* kbh = kn + (size_t)bh * Nn * Dd;
    const unsigned short* vbh = vt + (size_t)bh * Dd * Nn;
    unsigned short* Plw = Pl + w * 16 * PIT;
    int srow = t >> 3, se8 = (t & 7) * 8;          // staging row/col (c=0); c=1 adds 32 rows

    #pragma unroll
    for (int pass = 0; pass < 2; ++pass) {
        int qt = pass == 0 ? (int)blockIdx.x : (NTQ - 1 - (int)blockIdx.x);
        int q0 = qt * 64;
        int qrow = q0 + w * 16 + col;
        const unsigned short* qp = qn + ((size_t)bh * Nn + qrow) * Dd;
        short8 qf0 = *(const short8*)(qp + quad * 8);
        short8 qf1 = *(const short8*)(qp + 32 + quad * 8);

        f32x4 O[4];
        #pragma unroll
        for (int i = 0; i < 4; ++i) O[i] = (f32x4){0.f, 0.f, 0.f, 0.f};
        float m = NEG_BIG, l = 0.0f;
        int ntiles = qt + 1;

        __syncthreads();   // buffers free from previous pass
        // prologue: stage tile 0 -> buf 0
        #pragma unroll
        for (int c = 0; c < 2; ++c) {
            int row = srow + c * 32;
            *(uint4*)(Kb[0] + row * PIT + se8) =
                *(const uint4*)(kbh + (size_t)row * Dd + se8);
            *(uint4*)(Vb[0] + row * PIT + se8) =
                *(const uint4*)(vbh + (size_t)row * Nn + se8);
        }

        for (int tile = 0; tile < ntiles; ++tile) {
            int j0 = tile * 64;
            int cur = tile & 1, nxt = cur ^ 1;
            __syncthreads();   // buf[cur] ready; buf[nxt] free

            // issue next tile's global loads (land during compute)
            uint4 kr[2], vr[2];
            bool pf = (tile + 1) < ntiles;
            if (pf) {
                int jn = j0 + 64;
                #pragma unroll
                for (int c = 0; c < 2; ++c) {
                    int row = srow + c * 32;
                    kr[c] = *(const uint4*)(kbh + (size_t)(jn + row) * Dd + se8);
                    vr[c] = *(const uint4*)(vbh + (size_t)row * Nn + jn + se8);
                }
            }

            // S^T = K . Q^T
            f32x4 S[4];
            #pragma unroll
            for (int i = 0; i < 4; ++i) S[i] = (f32x4){0.f, 0.f, 0.f, 0.f};
            {
                const unsigned short* kb = Kb[cur] + col * PIT + quad * 8;
                #pragma unroll
                for (int mt = 0; mt < 4; ++mt) {
                    short8 a0 = *(const short8*)(kb + mt * 16 * PIT);
                    S[mt] = __builtin_amdgcn_mfma_f32_16x16x32_bf16(a0, qf0, S[mt], 0, 0, 0);
                    short8 a1 = *(const short8*)(kb + mt * 16 * PIT + 32);
                    S[mt] = __builtin_amdgcn_mfma_f32_16x16x32_bf16(a1, qf1, S[mt], 0, 0, 0);
                }
            }
            if (j0 + 63 > q0 + w * 16) {   // diagonal tile: causal mask
                #pragma unroll
                for (int mt = 0; mt < 4; ++mt)
                    #pragma unroll
                    for (int r = 0; r < 4; ++r) {
                        int key = j0 + mt * 16 + quad * 4 + r;
                        if (key > qrow) S[mt][r] = NEG_BIG;
                    }
            }
            // online softmax (base-2 domain; log2e folded into q)
            float rmax = S[0][0];
            #pragma unroll
            for (int mt = 0; mt < 4; ++mt)
                #pragma unroll
                for (int r = 0; r < 4; ++r) rmax = fmaxf(rmax, S[mt][r]);
            rmax = fmaxf(rmax, __shfl_xor(rmax, 16, 64));
            rmax = fmaxf(rmax, __shfl_xor(rmax, 32, 64));
            float mn = fmaxf(m, rmax);
            float alpha = exp2f(m - mn);
            float P[4][4];
            float rsum = 0.0f;
            #pragma unroll
            for (int mt = 0; mt < 4; ++mt)
                #pragma unroll
                for (int r = 0; r < 4; ++r) {
                    P[mt][r] = exp2f(S[mt][r] - mn);
                    rsum += P[mt][r];
                }
            rsum += __shfl_xor(rsum, 16, 64);
            rsum += __shfl_xor(rsum, 32, 64);
            l = l * alpha + rsum;
            m = mn;
            #pragma unroll
            for (int i = 0; i < 4; ++i) O[i] *= alpha;
            #pragma unroll
            for (int mt = 0; mt < 4; ++mt) {
                uint2 uu;
                uu.x = f2bf(P[mt][0]) | (f2bf(P[mt][1]) << 16);
                uu.y = f2bf(P[mt][2]) | (f2bf(P[mt][3]) << 16);
                *(uint2*)(Plw + col * PIT + mt * 16 + quad * 4) = uu;
            }
            asm volatile("s_waitcnt lgkmcnt(0)" ::: "memory");
            short8 pf0 = *(const short8*)(Plw + col * PIT + quad * 8);
            short8 pf1 = *(const short8*)(Plw + col * PIT + 32 + quad * 8);
            // O^T += V^T . P^T
            {
                const unsigned short* vb = Vb[cur] + col * PIT + quad * 8;
                #pragma unroll
                for (int mt = 0; mt < 4; ++mt) {
                    short8 a0 = *(const short8*)(vb + mt * 16 * PIT);
                    O[mt] = __builtin_amdgcn_mfma_f32_16x16x32_bf16(a0, pf0, O[mt], 0, 0, 0);
                    short8 a1 = *(const short8*)(vb + mt * 16 * PIT + 32);
                    O[mt] = __builtin_amdgcn_mfma_f32_16x16x32_bf16(a1, pf1, O[mt], 0, 0, 0);
                }
            }
            // stage next tile into buf[nxt] (consumed at next barrier)
            if (pf) {
                #pragma unroll
                for (int c = 0; c < 2; ++c) {
                    int row = srow + c * 32;
                    *(uint4*)(Kb[nxt] + row * PIT + se8) = kr[c];
                    *(uint4*)(Vb[nxt] + row * PIT + se8) = vr[c];
                }
            }
        }
        float rl = 1.0f / l;
        unsigned short* yp = y + ((size_t)b * Nn + qrow) * Ee + h * Dd;
        #pragma unroll
        for (int mt = 0; mt < 4; ++mt) {
            f32x4 o = O[mt] * rl;
            uint2 uu;
            uu.x = f2bf(o[0]) | (f2bf(o[1]) << 16);
            uu.y = f2bf(o[2]) | (f2bf(o[3]) << 16);
            *(uint2*)(yp + mt * 16 + quad * 4) = uu;
        }
    }
}

// MFMA NT GEMM: out[m][e] = sum_f y[m][f]*W[e][f] + bias[e]
__global__ __launch_bounds__(256) void proj_kernel(
    const unsigned short* __restrict__ y, const unsigned short* __restrict__ w,
    const float* __restrict__ bias, float* __restrict__ out)
{
    __shared__ __align__(16) unsigned short Al[128 * PIT];
    __shared__ __align__(16) unsigned short Bl[128 * PIT];
    int t = threadIdx.x;
    int wv = t >> 6, lane = t & 63;
    int quad = lane >> 4, col = lane & 15;
    int wm = wv >> 1, wn = wv & 1;
    int e0 = blockIdx.x * 128, m0 = blockIdx.y * 128;
    f32x4 acc[4][4];
    #pragma unroll
    for (int i = 0; i < 4; ++i)
        #pragma unroll
        for (int j = 0; j < 4; ++j) acc[i][j] = (f32x4){0.f, 0.f, 0.f, 0.f};

    for (int k0 = 0; k0 < Ee; k0 += 64) {
        #pragma unroll
        for (int c = 0; c < 4; ++c) {
            int id = t + c * 256;
            int row = id >> 3, e8 = (id & 7) * 8;
            *(uint4*)(Al + row * PIT + e8) =
                *(const uint4*)(y + (size_t)(m0 + row) * Ee + k0 + e8);
            *(uint4*)(Bl + row * PIT + e8) =
                *(const uint4*)(w + (size_t)(e0 + row) * Ee + k0 + e8);
        }
        __syncthreads();
        #pragma unroll
        for (int kc = 0; kc < 2; ++kc) {
            short8 a[4], bb[4];
            #pragma unroll
            for (int mi = 0; mi < 4; ++mi)
                a[mi] = *(const short8*)(Al + (wm * 64 + mi * 16 + col) * PIT + kc * 32 + quad * 8);
            #pragma unroll
            for (int ni = 0; ni < 4; ++ni)
                bb[ni] = *(const short8*)(Bl + (wn * 64 + ni * 16 + col) * PIT + kc * 32 + quad * 8);
            #pragma unroll
            for (int mi = 0; mi < 4; ++mi)
                #pragma unroll
                for (int ni = 0; ni < 4; ++ni)
                    acc[mi][ni] = __builtin_amdgcn_mfma_f32_16x16x32_bf16(a[mi], bb[ni], acc[mi][ni], 0, 0, 0);
        }
        __syncthreads();
    }
    #pragma unroll
    for (int ni = 0; ni < 4; ++ni) {
        int e = e0 + wn * 64 + ni * 16 + col;
        float be = bias[e];
        #pragma unroll
        for (int mi = 0; mi < 4; ++mi) {
            int mrow = m0 + wm * 64 + mi * 16 + quad * 4;
            #pragma unroll
            for (int r = 0; r < 4; ++r)
                out[(size_t)(mrow + r) * Ee + e] = acc[mi][ni][r] + be;
        }
    }
}

extern "C" void kernel_launch(void* const* d_in, const int* in_sizes, int n_in,
                              void* d_out, int out_size, void* d_ws, size_t ws_size,
                              hipStream_t stream) {
    const float* q      = (const float*)d_in[0];
    const float* k      = (const float*)d_in[1];
    const float* v      = (const float*)d_in[2];
    const float* qscale = (const float*)d_in[3];
    const float* kscale = (const float*)d_in[4];
    const float* projw  = (const float*)d_in[5];
    const float* projb  = (const float*)d_in[6];
    float* out = (float*)d_out;

    char* base = (char*)d_ws;
    float* ctab  = (float*)(base);
    float* stab  = (float*)(base + 131072);
    float* sctab = (float*)(base + 262144);
    unsigned short* qn   = (unsigned short*)(base + 393216);
    unsigned short* kn   = (unsigned short*)(base + 12976128);
    unsigned short* vt   = (unsigned short*)(base + 25559040);
    unsigned short* yatt = (unsigned short*)(base + 38141952);
    unsigned short* wb   = (unsigned short*)(base + 50724864);

    tab_kernel<<<(Nn * 16 + 255) / 256, 256, 0, stream>>>(ctab, stab, sctab);
    prep_kernel<<<(Bb * Hh * Nn) / 4, 256, 0, stream>>>(
        q, k, qscale, kscale, ctab, stab, sctab, qn, kn);
    vt_kernel<<<Bb * Hh * 32, 256, 0, stream>>>(v, vt);
    wcvt_kernel<<<(Ee * Ee / 4) / 256, 256, 0, stream>>>(projw, wb);

    dim3 agrid(NTQ / 2, Bb * Hh);                        // (16, 48) paired q-tiles
    attn_kernel<<<agrid, 256, 0, stream>>>(qn, kn, vt, yatt);

    dim3 ggrid(Ee / 128, (Bb * Nn) / 128);               // (6, 64)
    proj_kernel<<<ggrid, 256, 0, stream>>>(yatt, wb, projb, out);
}

// Round 6
// 292.994 us; speedup vs baseline: 1.0764x; 1.0764x over previous
//
#include <hip/hip_runtime.h>
#include <hip/hip_bf16.h>
#include <math.h>

#define Bb 4
#define Nn 2048
#define Ee 768
#define Hh 12
#define Dd 64
#define RD 32
#define EPSf 1e-6f
#define NEG_BIG -3.0e38f
#define PIT 72   // bf16 pitch for 64-wide LDS tiles (16B-aligned rows, pad 8)
#define NTQ 32   // number of 64-row q tiles per (b,h)

typedef __attribute__((ext_vector_type(8))) short short8;
typedef __attribute__((ext_vector_type(4))) float f32x4;

__device__ inline float wave_reduce_sum(float v) {
    #pragma unroll
    for (int m = 1; m < 64; m <<= 1) v += __shfl_xor(v, m, 64);
    return v;
}

// scalar round-to-nearest-even fp32 -> bf16 bits (cheap kernels only)
__device__ inline unsigned f2bf(float x) {
    union { float f; unsigned u; } c; c.f = x;
    unsigned r = c.u + 0x7FFFu + ((c.u >> 16) & 1u);
    return r >> 16;
}

// packed fp32x2 -> bf16x2 (v_cvt_pk_bf16_f32)
__device__ inline unsigned pk_bf16(float a, float b) {
    union { __hip_bfloat162 h; unsigned u; } c;
    c.h = __float22bfloat162_rn(float2{a, b});
    return c.u;
}

// fp64-accurate rope/xpos tables: idx = n*16 + i
__global__ void tab_kernel(float* __restrict__ ctab, float* __restrict__ stab,
                           float* __restrict__ sctab) {
    int idx = blockIdx.x * 256 + threadIdx.x;
    if (idx >= Nn * 16) return;
    int n = idx >> 4, i = idx & 15;
    double inv_freq = pow(10000.0, -(double)(2 * i) / (double)RD);
    double ang = (double)n * inv_freq;
    ctab[idx] = (float)cos(ang);
    stab[idx] = (float)sin(ang);
    double base = (2.0 * (double)i + 0.4 * (double)RD) / (1.4 * (double)RD);
    double pw = ((double)n - (double)(Nn / 2)) / 512.0;
    sctab[idx] = (float)pow(base, pw);
}

// One wave per (b,h,n): RMS-norm + xPos rope; writes bf16 (B,H,N,D).
// 1/sqrt(D) * log2(e) folded into q so softmax uses exp2.
__global__ __launch_bounds__(256) void prep_kernel(
    const float* __restrict__ q, const float* __restrict__ k,
    const float* __restrict__ qscale, const float* __restrict__ kscale,
    const float* __restrict__ ctab, const float* __restrict__ stab,
    const float* __restrict__ sctab,
    unsigned short* __restrict__ qn, unsigned short* __restrict__ kn)
{
    int wave = blockIdx.x * 4 + (threadIdx.x >> 6);
    int lane = threadIdx.x & 63;
    int n  = wave % Nn;
    int bh = wave / Nn;
    int h  = bh % Hh;
    int b  = bh / Hh;
    int gidx = (b * Nn + n) * Ee + h * Dd + lane;
    float xq = q[gidx], xk = k[gidx];
    float msq = wave_reduce_sum(xq * xq) * (1.0f / 64.0f);
    float msk = wave_reduce_sum(xk * xk) * (1.0f / 64.0f);
    float xqn = xq * qscale[lane] * rsqrtf(msq + EPSf);
    float xkn = xk * kscale[lane] * rsqrtf(msk + EPSf);
    float pq = __shfl_xor(xqn, 1, 64);
    float pk = __shfl_xor(xkn, 1, 64);
    float oq = xqn, ok = xkn;
    if (lane < RD) {
        int i = lane >> 1;
        float c  = ctab[n * 16 + i];
        float s  = stab[n * 16 + i];
        float sc = sctab[n * 16 + i];
        float rq = (lane & 1) ? pq : -pq;
        float rk = (lane & 1) ? pk : -pk;
        oq = (xqn * c + rq * s) * sc;
        ok = (xkn * c + rk * s) / sc;
    }
    oq *= 0.125f * 1.44269504088896f;   // 1/sqrt(D) * log2(e)
    size_t oidx = (size_t)bh * (Nn * Dd) + (size_t)n * Dd + lane;
    qn[oidx] = (unsigned short)f2bf(oq);
    kn[oidx] = (unsigned short)f2bf(ok);
}

// Transpose V: (B,N,E) fp32 -> (B,H,D,N) bf16
__global__ __launch_bounds__(256) void vt_kernel(
    const float* __restrict__ v, unsigned short* __restrict__ vt)
{
    __shared__ float Vl[64 * 65];
    int t = threadIdx.x;
    int bh = blockIdx.x >> 5;
    int n0 = (blockIdx.x & 31) * 64;
    int b = bh / Hh, h = bh % Hh;
    const float4* v4 = (const float4*)v;
    #pragma unroll
    for (int c = 0; c < 4; ++c) {
        int idx = t + c * 256;
        int n = idx >> 4, d4 = idx & 15;
        float4 vv = v4[(size_t)(b * Nn + n0 + n) * (Ee / 4) + h * 16 + d4];
        int la = n * 65 + d4 * 4;
        Vl[la] = vv.x; Vl[la + 1] = vv.y; Vl[la + 2] = vv.z; Vl[la + 3] = vv.w;
    }
    __syncthreads();
    #pragma unroll
    for (int c = 0; c < 16; ++c) {
        int linear = t + c * 256;
        int d = linear >> 6, n = linear & 63;
        vt[((size_t)bh * Dd + d) * Nn + n0 + n] = (unsigned short)f2bf(Vl[n * 65 + d]);
    }
}

// W (E,E) fp32 -> bf16
__global__ __launch_bounds__(256) void wcvt_kernel(
    const float* __restrict__ w, unsigned short* __restrict__ wb)
{
    int idx = blockIdx.x * 256 + threadIdx.x;
    float4 v = ((const float4*)w)[idx];
    uint2 uu;
    uu.x = pk_bf16(v.x, v.y);
    uu.y = pk_bf16(v.z, v.w);
    *(uint2*)(wb + (size_t)idx * 4) = uu;
}

// MFMA flash attention (causal), balanced, single-buffered with reg prefetch.
// Block x handles q-tile x then (NTQ-1-x): every block does 33 tile-steps.
// Per tile: sync -> store staged regs to LDS -> sync -> issue next tile's
// global loads -> compute (loads land during compute; no extra LDS).
__global__ __launch_bounds__(256) void attn_kernel(
    const unsigned short* __restrict__ qn, const unsigned short* __restrict__ kn,
    const unsigned short* __restrict__ vt, unsigned short* __restrict__ y)
{
    __shared__ __align__(16) unsigned short Kl[64 * PIT];
    __shared__ __align__(16) unsigned short Vl[64 * PIT];   // V^T: [dim][key]
    __shared__ __align__(16) unsigned short Pl[4 * 16 * PIT];
    int t = threadIdx.x;
    int w = t >> 6, lane = t & 63;
    int quad = lane >> 4, col = lane & 15;
    int bh = blockIdx.y;
    int b = bh / Hh, h = bh % Hh;
    const unsigned short* kbh = kn + (size_t)bh * Nn * Dd;
    const unsigned short* vbh = vt + (size_t)bh * Dd * Nn;
    unsigned short* Plw = Pl + w * 16 * PIT;
    int srow = t >> 3, se8 = (t & 7) * 8;   // staging: c=0 rows 0..31, c=1 rows 32..63

    #pragma unroll
    for (int pass = 0; pass < 2; ++pass) {
        int qt = pass == 0 ? (int)blockIdx.x : (NTQ - 1 - (int)blockIdx.x);
        int q0 = qt * 64;
        int qrow = q0 + w * 16 + col;
        const unsigned short* qp = qn + ((size_t)bh * Nn + qrow) * Dd;
        short8 qf0 = *(const short8*)(qp + quad * 8);
        short8 qf1 = *(const short8*)(qp + 32 + quad * 8);

        f32x4 O[4];
        #pragma unroll
        for (int i = 0; i < 4; ++i) O[i] = (f32x4){0.f, 0.f, 0.f, 0.f};
        float m = NEG_BIG, l = 0.0f;
        int ntiles = qt + 1;

        // prologue: load tile 0 into regs
        uint4 kr[2], vr[2];
        #pragma unroll
        for (int c = 0; c < 2; ++c) {
            int row = srow + c * 32;
            kr[c] = *(const uint4*)(kbh + (size_t)row * Dd + se8);
            vr[c] = *(const uint4*)(vbh + (size_t)row * Nn + se8);
        }

        for (int tile = 0; tile < ntiles; ++tile) {
            int j0 = tile * 64;
            __syncthreads();   // previous tile's readers done
            #pragma unroll
            for (int c = 0; c < 2; ++c) {
                int row = srow + c * 32;
                *(uint4*)(Kl + row * PIT + se8) = kr[c];
                *(uint4*)(Vl + row * PIT + se8) = vr[c];
            }
            __syncthreads();   // tile visible

            // issue next tile's global loads; they land during compute
            if (tile + 1 < ntiles) {
                int jn = j0 + 64;
                #pragma unroll
                for (int c = 0; c < 2; ++c) {
                    int row = srow + c * 32;
                    kr[c] = *(const uint4*)(kbh + (size_t)(jn + row) * Dd + se8);
                    vr[c] = *(const uint4*)(vbh + (size_t)row * Nn + jn + se8);
                }
            }

            // S^T = K . Q^T
            f32x4 S[4];
            #pragma unroll
            for (int i = 0; i < 4; ++i) S[i] = (f32x4){0.f, 0.f, 0.f, 0.f};
            {
                const unsigned short* kb = Kl + col * PIT + quad * 8;
                #pragma unroll
                for (int mt = 0; mt < 4; ++mt) {
                    short8 a0 = *(const short8*)(kb + mt * 16 * PIT);
                    S[mt] = __builtin_amdgcn_mfma_f32_16x16x32_bf16(a0, qf0, S[mt], 0, 0, 0);
                    short8 a1 = *(const short8*)(kb + mt * 16 * PIT + 32);
                    S[mt] = __builtin_amdgcn_mfma_f32_16x16x32_bf16(a1, qf1, S[mt], 0, 0, 0);
                }
            }
            if (j0 + 63 > q0 + w * 16) {   // diagonal tile: causal mask
                #pragma unroll
                for (int mt = 0; mt < 4; ++mt)
                    #pragma unroll
                    for (int r = 0; r < 4; ++r) {
                        int key = j0 + mt * 16 + quad * 4 + r;
                        if (key > qrow) S[mt][r] = NEG_BIG;
                    }
            }
            // online softmax (base-2; log2e folded into q)
            float rmax = S[0][0];
            #pragma unroll
            for (int mt = 0; mt < 4; ++mt)
                #pragma unroll
                for (int r = 0; r < 4; ++r) rmax = fmaxf(rmax, S[mt][r]);
            rmax = fmaxf(rmax, __shfl_xor(rmax, 16, 64));
            rmax = fmaxf(rmax, __shfl_xor(rmax, 32, 64));
            float mn = fmaxf(m, rmax);
            float alpha = exp2f(m - mn);
            float P[4][4];
            float rsum = 0.0f;
            #pragma unroll
            for (int mt = 0; mt < 4; ++mt)
                #pragma unroll
                for (int r = 0; r < 4; ++r) {
                    P[mt][r] = exp2f(S[mt][r] - mn);
                    rsum += P[mt][r];
                }
            rsum += __shfl_xor(rsum, 16, 64);
            rsum += __shfl_xor(rsum, 32, 64);
            l = l * alpha + rsum;
            m = mn;
            #pragma unroll
            for (int i = 0; i < 4; ++i) O[i] *= alpha;
            #pragma unroll
            for (int mt = 0; mt < 4; ++mt) {
                uint2 uu;
                uu.x = pk_bf16(P[mt][0], P[mt][1]);
                uu.y = pk_bf16(P[mt][2], P[mt][3]);
                *(uint2*)(Plw + col * PIT + mt * 16 + quad * 4) = uu;
            }
            asm volatile("s_waitcnt lgkmcnt(0)" ::: "memory");
            short8 pf0 = *(const short8*)(Plw + col * PIT + quad * 8);
            short8 pf1 = *(const short8*)(Plw + col * PIT + 32 + quad * 8);
            // O^T += V^T . P^T
            {
                const unsigned short* vb = Vl + col * PIT + quad * 8;
                #pragma unroll
                for (int mt = 0; mt < 4; ++mt) {
                    short8 a0 = *(const short8*)(vb + mt * 16 * PIT);
                    O[mt] = __builtin_amdgcn_mfma_f32_16x16x32_bf16(a0, pf0, O[mt], 0, 0, 0);
                    short8 a1 = *(const short8*)(vb + mt * 16 * PIT + 32);
                    O[mt] = __builtin_amdgcn_mfma_f32_16x16x32_bf16(a1, pf1, O[mt], 0, 0, 0);
                }
            }
        }
        float rl = 1.0f / l;
        unsigned short* yp = y + ((size_t)b * Nn + qrow) * Ee + h * Dd;
        #pragma unroll
        for (int mt = 0; mt < 4; ++mt) {
            f32x4 o = O[mt] * rl;
            uint2 uu;
            uu.x = pk_bf16(o[0], o[1]);
            uu.y = pk_bf16(o[2], o[3]);
            *(uint2*)(yp + mt * 16 + quad * 4) = uu;
        }
    }
}

// MFMA NT GEMM: out[m][e] = sum_f y[m][f]*W[e][f] + bias[e]
__global__ __launch_bounds__(256) void proj_kernel(
    const unsigned short* __restrict__ y, const unsigned short* __restrict__ w,
    const float* __restrict__ bias, float* __restrict__ out)
{
    __shared__ __align__(16) unsigned short Al[128 * PIT];
    __shared__ __align__(16) unsigned short Bl[128 * PIT];
    int t = threadIdx.x;
    int wv = t >> 6, lane = t & 63;
    int quad = lane >> 4, col = lane & 15;
    int wm = wv >> 1, wn = wv & 1;
    int e0 = blockIdx.x * 128, m0 = blockIdx.y * 128;
    f32x4 acc[4][4];
    #pragma unroll
    for (int i = 0; i < 4; ++i)
        #pragma unroll
        for (int j = 0; j < 4; ++j) acc[i][j] = (f32x4){0.f, 0.f, 0.f, 0.f};

    for (int k0 = 0; k0 < Ee; k0 += 64) {
        #pragma unroll
        for (int c = 0; c < 4; ++c) {
            int id = t + c * 256;
            int row = id >> 3, e8 = (id & 7) * 8;
            *(uint4*)(Al + row * PIT + e8) =
                *(const uint4*)(y + (size_t)(m0 + row) * Ee + k0 + e8);
            *(uint4*)(Bl + row * PIT + e8) =
                *(const uint4*)(w + (size_t)(e0 + row) * Ee + k0 + e8);
        }
        __syncthreads();
        #pragma unroll
        for (int kc = 0; kc < 2; ++kc) {
            short8 a[4], bb[4];
            #pragma unroll
            for (int mi = 0; mi < 4; ++mi)
                a[mi] = *(const short8*)(Al + (wm * 64 + mi * 16 + col) * PIT + kc * 32 + quad * 8);
            #pragma unroll
            for (int ni = 0; ni < 4; ++ni)
                bb[ni] = *(const short8*)(Bl + (wn * 64 + ni * 16 + col) * PIT + kc * 32 + quad * 8);
            #pragma unroll
            for (int mi = 0; mi < 4; ++mi)
                #pragma unroll
                for (int ni = 0; ni < 4; ++ni)
                    acc[mi][ni] = __builtin_amdgcn_mfma_f32_16x16x32_bf16(a[mi], bb[ni], acc[mi][ni], 0, 0, 0);
        }
        __syncthreads();
    }
    #pragma unroll
    for (int ni = 0; ni < 4; ++ni) {
        int e = e0 + wn * 64 + ni * 16 + col;
        float be = bias[e];
        #pragma unroll
        for (int mi = 0; mi < 4; ++mi) {
            int mrow = m0 + wm * 64 + mi * 16 + quad * 4;
            #pragma unroll
            for (int r = 0; r < 4; ++r)
                out[(size_t)(mrow + r) * Ee + e] = acc[mi][ni][r] + be;
        }
    }
}

extern "C" void kernel_launch(void* const* d_in, const int* in_sizes, int n_in,
                              void* d_out, int out_size, void* d_ws, size_t ws_size,
                              hipStream_t stream) {
    const float* q      = (const float*)d_in[0];
    const float* k      = (const float*)d_in[1];
    const float* v      = (const float*)d_in[2];
    const float* qscale = (const float*)d_in[3];
    const float* kscale = (const float*)d_in[4];
    const float* projw  = (const float*)d_in[5];
    const float* projb  = (const float*)d_in[6];
    float* out = (float*)d_out;

    char* base = (char*)d_ws;
    float* ctab  = (float*)(base);
    float* stab  = (float*)(base + 131072);
    float* sctab = (float*)(base + 262144);
    unsigned short* qn   = (unsigned short*)(base + 393216);
    unsigned short* kn   = (unsigned short*)(base + 12976128);
    unsigned short* vt   = (unsigned short*)(base + 25559040);
    unsigned short* yatt = (unsigned short*)(base + 38141952);
    unsigned short* wb   = (unsigned short*)(base + 50724864);

    tab_kernel<<<(Nn * 16 + 255) / 256, 256, 0, stream>>>(ctab, stab, sctab);
    prep_kernel<<<(Bb * Hh * Nn) / 4, 256, 0, stream>>>(
        q, k, qscale, kscale, ctab, stab, sctab, qn, kn);
    vt_kernel<<<Bb * Hh * 32, 256, 0, stream>>>(v, vt);
    wcvt_kernel<<<(Ee * Ee / 4) / 256, 256, 0, stream>>>(projw, wb);

    dim3 agrid(NTQ / 2, Bb * Hh);                        // (16, 48) paired q-tiles
    attn_kernel<<<agrid, 256, 0, stream>>>(qn, kn, vt, yatt);

    dim3 ggrid(Ee / 128, (Bb * Nn) / 128);               // (6, 64)
    proj_kernel<<<ggrid, 256, 0, stream>>>(yatt, wb, projb, out);
}

// Round 7
// 241.519 us; speedup vs baseline: 1.3058x; 1.2131x over previous
//
#include <hip/hip_runtime.h>
#include <hip/hip_bf16.h>
#include <math.h>

#define Bb 4
#define Nn 2048
#define Ee 768
#define Hh 12
#define Dd 64
#define RD 32
#define EPSf 1e-6f
#define NEG_BIG -3.0e38f
#define PIT 72   // bf16 pitch for padded (manual) LDS tiles
#define NTQ 32   // number of 64-row q tiles per (b,h)

typedef __attribute__((ext_vector_type(8))) short short8;
typedef __attribute__((ext_vector_type(4))) float f32x4;

__device__ inline float wave_reduce_sum(float v) {
    #pragma unroll
    for (int m = 1; m < 64; m <<= 1) v += __shfl_xor(v, m, 64);
    return v;
}

// scalar round-to-nearest-even fp32 -> bf16 bits (cheap kernels only)
__device__ inline unsigned f2bf(float x) {
    union { float f; unsigned u; } c; c.f = x;
    unsigned r = c.u + 0x7FFFu + ((c.u >> 16) & 1u);
    return r >> 16;
}

// packed fp32x2 -> bf16x2 (v_cvt_pk_bf16_f32)
__device__ inline unsigned pk_bf16(float a, float b) {
    union { __hip_bfloat162 h; unsigned u; } c;
    c.h = __float22bfloat162_rn(float2{a, b});
    return c.u;
}

// async global->LDS DMA, 16 B per lane; lds dest = uniform base + lane*16
__device__ inline void gload16(const void* g, void* l) {
    __builtin_amdgcn_global_load_lds(
        (const __attribute__((address_space(1))) void*)g,
        (__attribute__((address_space(3))) void*)l,
        16, 0, 0);
}

// fp64-accurate rope/xpos tables: idx = n*16 + i
__global__ void tab_kernel(float* __restrict__ ctab, float* __restrict__ stab,
                           float* __restrict__ sctab) {
    int idx = blockIdx.x * 256 + threadIdx.x;
    if (idx >= Nn * 16) return;
    int n = idx >> 4, i = idx & 15;
    double inv_freq = pow(10000.0, -(double)(2 * i) / (double)RD);
    double ang = (double)n * inv_freq;
    ctab[idx] = (float)cos(ang);
    stab[idx] = (float)sin(ang);
    double base = (2.0 * (double)i + 0.4 * (double)RD) / (1.4 * (double)RD);
    double pw = ((double)n - (double)(Nn / 2)) / 512.0;
    sctab[idx] = (float)pow(base, pw);
}

// One wave per (b,h,n): RMS-norm + xPos rope; writes bf16 (B,H,N,D).
// 1/sqrt(D) * log2(e) folded into q so softmax uses exp2.
__global__ __launch_bounds__(256) void prep_kernel(
    const float* __restrict__ q, const float* __restrict__ k,
    const float* __restrict__ qscale, const float* __restrict__ kscale,
    const float* __restrict__ ctab, const float* __restrict__ stab,
    const float* __restrict__ sctab,
    unsigned short* __restrict__ qn, unsigned short* __restrict__ kn)
{
    int wave = blockIdx.x * 4 + (threadIdx.x >> 6);
    int lane = threadIdx.x & 63;
    int n  = wave % Nn;
    int bh = wave / Nn;
    int h  = bh % Hh;
    int b  = bh / Hh;
    int gidx = (b * Nn + n) * Ee + h * Dd + lane;
    float xq = q[gidx], xk = k[gidx];
    float msq = wave_reduce_sum(xq * xq) * (1.0f / 64.0f);
    float msk = wave_reduce_sum(xk * xk) * (1.0f / 64.0f);
    float xqn = xq * qscale[lane] * rsqrtf(msq + EPSf);
    float xkn = xk * kscale[lane] * rsqrtf(msk + EPSf);
    float pq = __shfl_xor(xqn, 1, 64);
    float pk = __shfl_xor(xkn, 1, 64);
    float oq = xqn, ok = xkn;
    if (lane < RD) {
        int i = lane >> 1;
        float c  = ctab[n * 16 + i];
        float s  = stab[n * 16 + i];
        float sc = sctab[n * 16 + i];
        float rq = (lane & 1) ? pq : -pq;
        float rk = (lane & 1) ? pk : -pk;
        oq = (xqn * c + rq * s) * sc;
        ok = (xkn * c + rk * s) / sc;
    }
    oq *= 0.125f * 1.44269504088896f;   // 1/sqrt(D) * log2(e)
    size_t oidx = (size_t)bh * (Nn * Dd) + (size_t)n * Dd + lane;
    qn[oidx] = (unsigned short)f2bf(oq);
    kn[oidx] = (unsigned short)f2bf(ok);
}

// Transpose V: (B,N,E) fp32 -> (B,H,D,N) bf16
__global__ __launch_bounds__(256) void vt_kernel(
    const float* __restrict__ v, unsigned short* __restrict__ vt)
{
    __shared__ float Vl[64 * 65];
    int t = threadIdx.x;
    int bh = blockIdx.x >> 5;
    int n0 = (blockIdx.x & 31) * 64;
    int b = bh / Hh, h = bh % Hh;
    const float4* v4 = (const float4*)v;
    #pragma unroll
    for (int c = 0; c < 4; ++c) {
        int idx = t + c * 256;
        int n = idx >> 4, d4 = idx & 15;
        float4 vv = v4[(size_t)(b * Nn + n0 + n) * (Ee / 4) + h * 16 + d4];
        int la = n * 65 + d4 * 4;
        Vl[la] = vv.x; Vl[la + 1] = vv.y; Vl[la + 2] = vv.z; Vl[la + 3] = vv.w;
    }
    __syncthreads();
    #pragma unroll
    for (int c = 0; c < 16; ++c) {
        int linear = t + c * 256;
        int d = linear >> 6, n = linear & 63;
        vt[((size_t)bh * Dd + d) * Nn + n0 + n] = (unsigned short)f2bf(Vl[n * 65 + d]);
    }
}

// W (E,E) fp32 -> bf16
__global__ __launch_bounds__(256) void wcvt_kernel(
    const float* __restrict__ w, unsigned short* __restrict__ wb)
{
    int idx = blockIdx.x * 256 + threadIdx.x;
    float4 v = ((const float4*)w)[idx];
    uint2 uu;
    uu.x = pk_bf16(v.x, v.y);
    uu.y = pk_bf16(v.z, v.w);
    *(uint2*)(wb + (size_t)idx * 4) = uu;
}

// MFMA flash attention (causal), balanced pairs, async-DMA staged K/V.
// K/V LDS tiles: pitch 64 (no pad), XOR chunk swizzle — LDS row r slot cc
// (16B chunks) holds global chunk cc^(r&7). DMA dest is lane-contiguous;
// fragment reads index slot (want ^ (row&7)) => 2-way max (free).
__global__ __launch_bounds__(256) void attn_kernel(
    const unsigned short* __restrict__ qn, const unsigned short* __restrict__ kn,
    const unsigned short* __restrict__ vt, unsigned short* __restrict__ y)
{
    __shared__ __align__(16) unsigned short Kl[64 * 64];
    __shared__ __align__(16) unsigned short Vl[64 * 64];    // V^T: [dim][key]
    __shared__ __align__(16) unsigned short Pl[4 * 16 * PIT];
    int t = threadIdx.x;
    int w = t >> 6, lane = t & 63;
    int quad = lane >> 4, col = lane & 15;
    int bh = blockIdx.y;
    int b = bh / Hh, h = bh % Hh;
    const unsigned short* kbh = kn + (size_t)bh * Nn * Dd;
    const unsigned short* vbh = vt + (size_t)bh * Dd * Nn;
    unsigned short* Plw = Pl + w * 16 * PIT;

    // staging (per-lane, tile-invariant): wave w instr c covers LDS rows
    // 16w+8c .. +7; lane l -> row 16w+8c+(l>>3), slot l&7, global chunk (l&7)^(l>>3)
    int l8 = lane >> 3, c8 = lane & 7;
    int g8 = (c8 ^ l8) * 8;                 // element offset of source chunk
    // fragment-read slot offsets (swizzled)
    int sw = col & 7;
    int i0 = ((quad    ) ^ sw) * 8;         // k-dims/keys 0..31 chunk
    int i1 = ((quad + 4) ^ sw) * 8;         // k-dims/keys 32..63 chunk

    #pragma unroll
    for (int pass = 0; pass < 2; ++pass) {
        int qt = pass == 0 ? (int)blockIdx.x : (NTQ - 1 - (int)blockIdx.x);
        int q0 = qt * 64;
        int qrow = q0 + w * 16 + col;
        const unsigned short* qp = qn + ((size_t)bh * Nn + qrow) * Dd;
        short8 qf0 = *(const short8*)(qp + quad * 8);
        short8 qf1 = *(const short8*)(qp + 32 + quad * 8);

        f32x4 O[4];
        #pragma unroll
        for (int i = 0; i < 4; ++i) O[i] = (f32x4){0.f, 0.f, 0.f, 0.f};
        float m = NEG_BIG, l = 0.0f;
        int ntiles = qt + 1;

        for (int tile = 0; tile < ntiles; ++tile) {
            int j0 = tile * 64;
            __syncthreads();   // previous tile's readers done
            // async DMA: K rows and V^T rows for this tile (no VGPR round-trip)
            #pragma unroll
            for (int c = 0; c < 2; ++c) {
                int r = w * 16 + c * 8 + l8;            // tile row this lane feeds
                int dstbase = (w * 16 + c * 8) * 64;    // wave-uniform LDS base
                gload16(kbh + ((size_t)(j0 + r) << 6) + g8, Kl + dstbase);
                gload16(vbh + (size_t)r * Nn + j0 + g8, Vl + dstbase);
            }
            __syncthreads();   // DMA drained (vmcnt before barrier) + visible

            // S^T = K . Q^T
            f32x4 S[4];
            #pragma unroll
            for (int i = 0; i < 4; ++i) S[i] = (f32x4){0.f, 0.f, 0.f, 0.f};
            #pragma unroll
            for (int mt = 0; mt < 4; ++mt) {
                const unsigned short* rowp = Kl + (col + 16 * mt) * 64;
                short8 a0 = *(const short8*)(rowp + i0);
                S[mt] = __builtin_amdgcn_mfma_f32_16x16x32_bf16(a0, qf0, S[mt], 0, 0, 0);
                short8 a1 = *(const short8*)(rowp + i1);
                S[mt] = __builtin_amdgcn_mfma_f32_16x16x32_bf16(a1, qf1, S[mt], 0, 0, 0);
            }
            if (j0 + 63 > q0 + w * 16) {   // diagonal tile: causal mask
                #pragma unroll
                for (int mt = 0; mt < 4; ++mt)
                    #pragma unroll
                    for (int r = 0; r < 4; ++r) {
                        int key = j0 + mt * 16 + quad * 4 + r;
                        if (key > qrow) S[mt][r] = NEG_BIG;
                    }
            }
            // online softmax (base-2; log2e folded into q)
            float rmax = S[0][0];
            #pragma unroll
            for (int mt = 0; mt < 4; ++mt)
                #pragma unroll
                for (int r = 0; r < 4; ++r) rmax = fmaxf(rmax, S[mt][r]);
            rmax = fmaxf(rmax, __shfl_xor(rmax, 16, 64));
            rmax = fmaxf(rmax, __shfl_xor(rmax, 32, 64));
            float mn = fmaxf(m, rmax);
            float alpha = exp2f(m - mn);
            float P[4][4];
            float rsum = 0.0f;
            #pragma unroll
            for (int mt = 0; mt < 4; ++mt)
                #pragma unroll
                for (int r = 0; r < 4; ++r) {
                    P[mt][r] = exp2f(S[mt][r] - mn);
                    rsum += P[mt][r];
                }
            rsum += __shfl_xor(rsum, 16, 64);
            rsum += __shfl_xor(rsum, 32, 64);
            l = l * alpha + rsum;
            m = mn;
            #pragma unroll
            for (int i = 0; i < 4; ++i) O[i] *= alpha;
            #pragma unroll
            for (int mt = 0; mt < 4; ++mt) {
                uint2 uu;
                uu.x = pk_bf16(P[mt][0], P[mt][1]);
                uu.y = pk_bf16(P[mt][2], P[mt][3]);
                *(uint2*)(Plw + col * PIT + mt * 16 + quad * 4) = uu;
            }
            asm volatile("s_waitcnt lgkmcnt(0)" ::: "memory");
            short8 pf0 = *(const short8*)(Plw + col * PIT + quad * 8);
            short8 pf1 = *(const short8*)(Plw + col * PIT + 32 + quad * 8);
            // O^T += V^T . P^T
            #pragma unroll
            for (int mt = 0; mt < 4; ++mt) {
                const unsigned short* rowp = Vl + (col + 16 * mt) * 64;
                short8 a0 = *(const short8*)(rowp + i0);
                O[mt] = __builtin_amdgcn_mfma_f32_16x16x32_bf16(a0, pf0, O[mt], 0, 0, 0);
                short8 a1 = *(const short8*)(rowp + i1);
                O[mt] = __builtin_amdgcn_mfma_f32_16x16x32_bf16(a1, pf1, O[mt], 0, 0, 0);
            }
        }
        float rl = 1.0f / l;
        unsigned short* yp = y + ((size_t)b * Nn + qrow) * Ee + h * Dd;
        #pragma unroll
        for (int mt = 0; mt < 4; ++mt) {
            f32x4 o = O[mt] * rl;
            uint2 uu;
            uu.x = pk_bf16(o[0], o[1]);
            uu.y = pk_bf16(o[2], o[3]);
            *(uint2*)(yp + mt * 16 + quad * 4) = uu;
        }
    }
}

// MFMA NT GEMM: out[m][e] = sum_f y[m][f]*W[e][f] + bias[e]
__global__ __launch_bounds__(256) void proj_kernel(
    const unsigned short* __restrict__ y, const unsigned short* __restrict__ w,
    const float* __restrict__ bias, float* __restrict__ out)
{
    __shared__ __align__(16) unsigned short Al[128 * PIT];
    __shared__ __align__(16) unsigned short Bl[128 * PIT];
    int t = threadIdx.x;
    int wv = t >> 6, lane = t & 63;
    int quad = lane >> 4, col = lane & 15;
    int wm = wv >> 1, wn = wv & 1;
    int e0 = blockIdx.x * 128, m0 = blockIdx.y * 128;
    f32x4 acc[4][4];
    #pragma unroll
    for (int i = 0; i < 4; ++i)
        #pragma unroll
        for (int j = 0; j < 4; ++j) acc[i][j] = (f32x4){0.f, 0.f, 0.f, 0.f};

    for (int k0 = 0; k0 < Ee; k0 += 64) {
        #pragma unroll
        for (int c = 0; c < 4; ++c) {
            int id = t + c * 256;
            int row = id >> 3, e8 = (id & 7) * 8;
            *(uint4*)(Al + row * PIT + e8) =
                *(const uint4*)(y + (size_t)(m0 + row) * Ee + k0 + e8);
            *(uint4*)(Bl + row * PIT + e8) =
                *(const uint4*)(w + (size_t)(e0 + row) * Ee + k0 + e8);
        }
        __syncthreads();
        #pragma unroll
        for (int kc = 0; kc < 2; ++kc) {
            short8 a[4], bb[4];
            #pragma unroll
            for (int mi = 0; mi < 4; ++mi)
                a[mi] = *(const short8*)(Al + (wm * 64 + mi * 16 + col) * PIT + kc * 32 + quad * 8);
            #pragma unroll
            for (int ni = 0; ni < 4; ++ni)
                bb[ni] = *(const short8*)(Bl + (wn * 64 + ni * 16 + col) * PIT + kc * 32 + quad * 8);
            #pragma unroll
            for (int mi = 0; mi < 4; ++mi)
                #pragma unroll
                for (int ni = 0; ni < 4; ++ni)
                    acc[mi][ni] = __builtin_amdgcn_mfma_f32_16x16x32_bf16(a[mi], bb[ni], acc[mi][ni], 0, 0, 0);
        }
        __syncthreads();
    }
    #pragma unroll
    for (int ni = 0; ni < 4; ++ni) {
        int e = e0 + wn * 64 + ni * 16 + col;
        float be = bias[e];
        #pragma unroll
        for (int mi = 0; mi < 4; ++mi) {
            int mrow = m0 + wm * 64 + mi * 16 + quad * 4;
            #pragma unroll
            for (int r = 0; r < 4; ++r)
                out[(size_t)(mrow + r) * Ee + e] = acc[mi][ni][r] + be;
        }
    }
}

extern "C" void kernel_launch(void* const* d_in, const int* in_sizes, int n_in,
                              void* d_out, int out_size, void* d_ws, size_t ws_size,
                              hipStream_t stream) {
    const float* q      = (const float*)d_in[0];
    const float* k      = (const float*)d_in[1];
    const float* v      = (const float*)d_in[2];
    const float* qscale = (const float*)d_in[3];
    const float* kscale = (const float*)d_in[4];
    const float* projw  = (const float*)d_in[5];
    const float* projb  = (const float*)d_in[6];
    float* out = (float*)d_out;

    char* base = (char*)d_ws;
    float* ctab  = (float*)(base);
    float* stab  = (float*)(base + 131072);
    float* sctab = (float*)(base + 262144);
    unsigned short* qn   = (unsigned short*)(base + 393216);
    unsigned short* kn   = (unsigned short*)(base + 12976128);
    unsigned short* vt   = (unsigned short*)(base + 25559040);
    unsigned short* yatt = (unsigned short*)(base + 38141952);
    unsigned short* wb   = (unsigned short*)(base + 50724864);

    tab_kernel<<<(Nn * 16 + 255) / 256, 256, 0, stream>>>(ctab, stab, sctab);
    prep_kernel<<<(Bb * Hh * Nn) / 4, 256, 0, stream>>>(
        q, k, qscale, kscale, ctab, stab, sctab, qn, kn);
    vt_kernel<<<Bb * Hh * 32, 256, 0, stream>>>(v, vt);
    wcvt_kernel<<<(Ee * Ee / 4) / 256, 256, 0, stream>>>(projw, wb);

    dim3 agrid(NTQ / 2, Bb * Hh);                        // (16, 48) paired q-tiles
    attn_kernel<<<agrid, 256, 0, stream>>>(qn, kn, vt, yatt);

    dim3 ggrid(Ee / 128, (Bb * Nn) / 128);               // (6, 64)
    proj_kernel<<<ggrid, 256, 0, stream>>>(yatt, wb, projb, out);
}

// Round 8
// 233.577 us; speedup vs baseline: 1.3502x; 1.0340x over previous
//
#include <hip/hip_runtime.h>
#include <hip/hip_bf16.h>
#include <math.h>

#define Bb 4
#define Nn 2048
#define Ee 768
#define Hh 12
#define Dd 64
#define RD 32
#define EPSf 1e-6f
#define NEG_BIG -3.0e38f
#define PIT 72   // bf16 pitch for P scratch tiles
#define NTQ 32   // number of 64-row q tiles per (b,h)

typedef __attribute__((ext_vector_type(8))) short short8;
typedef __attribute__((ext_vector_type(4))) float f32x4;

__device__ inline float wave_reduce_sum(float v) {
    #pragma unroll
    for (int m = 1; m < 64; m <<= 1) v += __shfl_xor(v, m, 64);
    return v;
}

// scalar round-to-nearest-even fp32 -> bf16 bits (cheap kernels only)
__device__ inline unsigned f2bf(float x) {
    union { float f; unsigned u; } c; c.f = x;
    unsigned r = c.u + 0x7FFFu + ((c.u >> 16) & 1u);
    return r >> 16;
}

// packed fp32x2 -> bf16x2 (v_cvt_pk_bf16_f32)
__device__ inline unsigned pk_bf16(float a, float b) {
    union { __hip_bfloat162 h; unsigned u; } c;
    c.h = __float22bfloat162_rn(float2{a, b});
    return c.u;
}

// async global->LDS DMA, 16 B per lane; lds dest = uniform base + lane*16
__device__ inline void gload16(const void* g, void* l) {
    __builtin_amdgcn_global_load_lds(
        (const __attribute__((address_space(1))) void*)g,
        (__attribute__((address_space(3))) void*)l,
        16, 0, 0);
}

// Fused: rope/xpos tables (fp64) + W fp32->bf16 conversion.
// Blocks [0, 128): tables; blocks [128, 128+576): W convert.
__global__ __launch_bounds__(256) void misc_kernel(
    float* __restrict__ ctab, float* __restrict__ stab, float* __restrict__ sctab,
    const float* __restrict__ w, unsigned short* __restrict__ wb)
{
    int bx = blockIdx.x;
    if (bx < 128) {
        int idx = bx * 256 + threadIdx.x;
        int n = idx >> 4, i = idx & 15;
        double inv_freq = pow(10000.0, -(double)(2 * i) / (double)RD);
        double ang = (double)n * inv_freq;
        ctab[idx] = (float)cos(ang);
        stab[idx] = (float)sin(ang);
        double base = (2.0 * (double)i + 0.4 * (double)RD) / (1.4 * (double)RD);
        double pw = ((double)n - (double)(Nn / 2)) / 512.0;
        sctab[idx] = (float)pow(base, pw);
    } else {
        int idx = (bx - 128) * 256 + threadIdx.x;   // one float4 each
        float4 v = ((const float4*)w)[idx];
        uint2 uu;
        uu.x = pk_bf16(v.x, v.y);
        uu.y = pk_bf16(v.z, v.w);
        *(uint2*)(wb + (size_t)idx * 4) = uu;
    }
}

// One wave per (b,h,n): RMS-norm + xPos rope; writes bf16 (B,H,N,D).
// 1/sqrt(D) * log2(e) folded into q so softmax uses exp2.
__global__ __launch_bounds__(256) void prep_kernel(
    const float* __restrict__ q, const float* __restrict__ k,
    const float* __restrict__ qscale, const float* __restrict__ kscale,
    const float* __restrict__ ctab, const float* __restrict__ stab,
    const float* __restrict__ sctab,
    unsigned short* __restrict__ qn, unsigned short* __restrict__ kn)
{
    int wave = blockIdx.x * 4 + (threadIdx.x >> 6);
    int lane = threadIdx.x & 63;
    int n  = wave % Nn;
    int bh = wave / Nn;
    int h  = bh % Hh;
    int b  = bh / Hh;
    int gidx = (b * Nn + n) * Ee + h * Dd + lane;
    float xq = q[gidx], xk = k[gidx];
    float msq = wave_reduce_sum(xq * xq) * (1.0f / 64.0f);
    float msk = wave_reduce_sum(xk * xk) * (1.0f / 64.0f);
    float xqn = xq * qscale[lane] * rsqrtf(msq + EPSf);
    float xkn = xk * kscale[lane] * rsqrtf(msk + EPSf);
    float pq = __shfl_xor(xqn, 1, 64);
    float pk = __shfl_xor(xkn, 1, 64);
    float oq = xqn, ok = xkn;
    if (lane < RD) {
        int i = lane >> 1;
        float c  = ctab[n * 16 + i];
        float s  = stab[n * 16 + i];
        float sc = sctab[n * 16 + i];
        float rq = (lane & 1) ? pq : -pq;
        float rk = (lane & 1) ? pk : -pk;
        oq = (xqn * c + rq * s) * sc;
        ok = (xkn * c + rk * s) / sc;
    }
    oq *= 0.125f * 1.44269504088896f;   // 1/sqrt(D) * log2(e)
    size_t oidx = (size_t)bh * (Nn * Dd) + (size_t)n * Dd + lane;
    qn[oidx] = (unsigned short)f2bf(oq);
    kn[oidx] = (unsigned short)f2bf(ok);
}

// Transpose V: (B,N,E) fp32 -> (B,H,D,N) bf16
__global__ __launch_bounds__(256) void vt_kernel(
    const float* __restrict__ v, unsigned short* __restrict__ vt)
{
    __shared__ float Vl[64 * 65];
    int t = threadIdx.x;
    int bh = blockIdx.x >> 5;
    int n0 = (blockIdx.x & 31) * 64;
    int b = bh / Hh, h = bh % Hh;
    const float4* v4 = (const float4*)v;
    #pragma unroll
    for (int c = 0; c < 4; ++c) {
        int idx = t + c * 256;
        int n = idx >> 4, d4 = idx & 15;
        float4 vv = v4[(size_t)(b * Nn + n0 + n) * (Ee / 4) + h * 16 + d4];
        int la = n * 65 + d4 * 4;
        Vl[la] = vv.x; Vl[la + 1] = vv.y; Vl[la + 2] = vv.z; Vl[la + 3] = vv.w;
    }
    __syncthreads();
    #pragma unroll
    for (int c = 0; c < 16; ++c) {
        int linear = t + c * 256;
        int d = linear >> 6, n = linear & 63;
        vt[((size_t)bh * Dd + d) * Nn + n0 + n] = (unsigned short)f2bf(Vl[n * 65 + d]);
    }
}

// MFMA flash attention (causal), balanced pairs, async-DMA staged K/V.
// grid (48, 16): blockIdx.x = bh so linear_id%8 = bh%8 -> per-XCD K/V locality.
// K/V LDS tiles: pitch 64 (no pad), XOR 16B-chunk swizzle.
__global__ __launch_bounds__(256) void attn_kernel(
    const unsigned short* __restrict__ qn, const unsigned short* __restrict__ kn,
    const unsigned short* __restrict__ vt, unsigned short* __restrict__ y)
{
    __shared__ __align__(16) unsigned short Kl[64 * 64];
    __shared__ __align__(16) unsigned short Vl[64 * 64];    // V^T: [dim][key]
    __shared__ __align__(16) unsigned short Pl[4 * 16 * PIT];
    int t = threadIdx.x;
    int w = t >> 6, lane = t & 63;
    int quad = lane >> 4, col = lane & 15;
    int bh = blockIdx.x;
    int b = bh / Hh, h = bh % Hh;
    const unsigned short* kbh = kn + (size_t)bh * Nn * Dd;
    const unsigned short* vbh = vt + (size_t)bh * Dd * Nn;
    unsigned short* Plw = Pl + w * 16 * PIT;

    int l8 = lane >> 3, c8 = lane & 7;
    int g8 = (c8 ^ l8) * 8;                 // element offset of source chunk
    int sw = col & 7;
    int i0 = ((quad    ) ^ sw) * 8;         // chunks 0..31
    int i1 = ((quad + 4) ^ sw) * 8;         // chunks 32..63

    #pragma unroll
    for (int pass = 0; pass < 2; ++pass) {
        int qt = pass == 0 ? (int)blockIdx.y : (NTQ - 1 - (int)blockIdx.y);
        int q0 = qt * 64;
        int qrow = q0 + w * 16 + col;
        const unsigned short* qp = qn + ((size_t)bh * Nn + qrow) * Dd;
        short8 qf0 = *(const short8*)(qp + quad * 8);
        short8 qf1 = *(const short8*)(qp + 32 + quad * 8);

        f32x4 O[4];
        #pragma unroll
        for (int i = 0; i < 4; ++i) O[i] = (f32x4){0.f, 0.f, 0.f, 0.f};
        float m = NEG_BIG, l = 0.0f;
        int ntiles = qt + 1;

        for (int tile = 0; tile < ntiles; ++tile) {
            int j0 = tile * 64;
            __syncthreads();   // previous tile's readers done
            #pragma unroll
            for (int c = 0; c < 2; ++c) {
                int r = w * 16 + c * 8 + l8;            // tile row this lane feeds
                int dstbase = (w * 16 + c * 8) * 64;    // wave-uniform LDS base
                gload16(kbh + ((size_t)(j0 + r) << 6) + g8, Kl + dstbase);
                gload16(vbh + (size_t)r * Nn + j0 + g8, Vl + dstbase);
            }
            __syncthreads();   // DMA drained + visible

            // S^T = K . Q^T
            f32x4 S[4];
            #pragma unroll
            for (int i = 0; i < 4; ++i) S[i] = (f32x4){0.f, 0.f, 0.f, 0.f};
            #pragma unroll
            for (int mt = 0; mt < 4; ++mt) {
                const unsigned short* rowp = Kl + (col + 16 * mt) * 64;
                short8 a0 = *(const short8*)(rowp + i0);
                S[mt] = __builtin_amdgcn_mfma_f32_16x16x32_bf16(a0, qf0, S[mt], 0, 0, 0);
                short8 a1 = *(const short8*)(rowp + i1);
                S[mt] = __builtin_amdgcn_mfma_f32_16x16x32_bf16(a1, qf1, S[mt], 0, 0, 0);
            }
            if (j0 + 63 > q0 + w * 16) {   // diagonal tile: causal mask
                #pragma unroll
                for (int mt = 0; mt < 4; ++mt)
                    #pragma unroll
                    for (int r = 0; r < 4; ++r) {
                        int key = j0 + mt * 16 + quad * 4 + r;
                        if (key > qrow) S[mt][r] = NEG_BIG;
                    }
            }
            // online softmax (base-2; log2e folded into q)
            float rmax = S[0][0];
            #pragma unroll
            for (int mt = 0; mt < 4; ++mt)
                #pragma unroll
                for (int r = 0; r < 4; ++r) rmax = fmaxf(rmax, S[mt][r]);
            rmax = fmaxf(rmax, __shfl_xor(rmax, 16, 64));
            rmax = fmaxf(rmax, __shfl_xor(rmax, 32, 64));
            float mn = fmaxf(m, rmax);
            float alpha = exp2f(m - mn);
            float P[4][4];
            float rsum = 0.0f;
            #pragma unroll
            for (int mt = 0; mt < 4; ++mt)
                #pragma unroll
                for (int r = 0; r < 4; ++r) {
                    P[mt][r] = exp2f(S[mt][r] - mn);
                    rsum += P[mt][r];
                }
            rsum += __shfl_xor(rsum, 16, 64);
            rsum += __shfl_xor(rsum, 32, 64);
            l = l * alpha + rsum;
            m = mn;
            #pragma unroll
            for (int i = 0; i < 4; ++i) O[i] *= alpha;
            #pragma unroll
            for (int mt = 0; mt < 4; ++mt) {
                uint2 uu;
                uu.x = pk_bf16(P[mt][0], P[mt][1]);
                uu.y = pk_bf16(P[mt][2], P[mt][3]);
                *(uint2*)(Plw + col * PIT + mt * 16 + quad * 4) = uu;
            }
            asm volatile("s_waitcnt lgkmcnt(0)" ::: "memory");
            short8 pf0 = *(const short8*)(Plw + col * PIT + quad * 8);
            short8 pf1 = *(const short8*)(Plw + col * PIT + 32 + quad * 8);
            // O^T += V^T . P^T
            #pragma unroll
            for (int mt = 0; mt < 4; ++mt) {
                const unsigned short* rowp = Vl + (col + 16 * mt) * 64;
                short8 a0 = *(const short8*)(rowp + i0);
                O[mt] = __builtin_amdgcn_mfma_f32_16x16x32_bf16(a0, pf0, O[mt], 0, 0, 0);
                short8 a1 = *(const short8*)(rowp + i1);
                O[mt] = __builtin_amdgcn_mfma_f32_16x16x32_bf16(a1, pf1, O[mt], 0, 0, 0);
            }
        }
        float rl = 1.0f / l;
        unsigned short* yp = y + ((size_t)b * Nn + qrow) * Ee + h * Dd;
        #pragma unroll
        for (int mt = 0; mt < 4; ++mt) {
            f32x4 o = O[mt] * rl;
            uint2 uu;
            uu.x = pk_bf16(o[0], o[1]);
            uu.y = pk_bf16(o[2], o[3]);
            *(uint2*)(yp + mt * 16 + quad * 4) = uu;
        }
    }
}

// MFMA NT GEMM: out[m][e] = sum_f y[m][f]*W[e][f] + bias[e]
// 64(m) x 128(e) tile, BK=64, async-DMA + XOR swizzle staging, grid (6,128).
// Wave wv owns e-range wv*32: acc[mi 0..3][ni 0..1].
__global__ __launch_bounds__(256) void proj_kernel(
    const unsigned short* __restrict__ y, const unsigned short* __restrict__ w,
    const float* __restrict__ bias, float* __restrict__ out)
{
    __shared__ __align__(16) unsigned short Al[64 * 64];
    __shared__ __align__(16) unsigned short Bl[128 * 64];
    int t = threadIdx.x;
    int wv = t >> 6, lane = t & 63;
    int quad = lane >> 4, col = lane & 15;
    int e0 = blockIdx.x * 128, m0 = blockIdx.y * 64;
    int l8 = lane >> 3, c8 = lane & 7;
    int g8 = (c8 ^ l8) * 8;
    f32x4 acc[4][2];
    #pragma unroll
    for (int i = 0; i < 4; ++i)
        #pragma unroll
        for (int j = 0; j < 2; ++j) acc[i][j] = (f32x4){0.f, 0.f, 0.f, 0.f};

    for (int k0 = 0; k0 < Ee; k0 += 64) {
        __syncthreads();
        // A: 64 rows (m); wave wv feeds rows wv*16 .. +15
        #pragma unroll
        for (int c = 0; c < 2; ++c) {
            int r = wv * 16 + c * 8 + l8;
            gload16(y + (size_t)(m0 + r) * Ee + k0 + g8, Al + (wv * 16 + c * 8) * 64);
        }
        // B: 128 rows (e); wave wv feeds rows wv*32 .. +31
        #pragma unroll
        for (int c = 0; c < 4; ++c) {
            int r = wv * 32 + c * 8 + l8;
            gload16(w + (size_t)(e0 + r) * Ee + k0 + g8, Bl + (wv * 32 + c * 8) * 64);
        }
        __syncthreads();
        #pragma unroll
        for (int kc = 0; kc < 2; ++kc) {
            short8 a[4], bb[2];
            #pragma unroll
            for (int mi = 0; mi < 4; ++mi) {
                int row = mi * 16 + col;
                int sl = ((kc * 4 + quad) ^ (row & 7)) * 8;
                a[mi] = *(const short8*)(Al + row * 64 + sl);
            }
            #pragma unroll
            for (int ni = 0; ni < 2; ++ni) {
                int row = wv * 32 + ni * 16 + col;
                int sl = ((kc * 4 + quad) ^ (row & 7)) * 8;
                bb[ni] = *(const short8*)(Bl + row * 64 + sl);
            }
            #pragma unroll
            for (int mi = 0; mi < 4; ++mi)
                #pragma unroll
                for (int ni = 0; ni < 2; ++ni)
                    acc[mi][ni] = __builtin_amdgcn_mfma_f32_16x16x32_bf16(a[mi], bb[ni], acc[mi][ni], 0, 0, 0);
        }
    }
    // C layout: e-col = col, m-row = quad*4 + r
    #pragma unroll
    for (int ni = 0; ni < 2; ++ni) {
        int e = e0 + wv * 32 + ni * 16 + col;
        float be = bias[e];
        #pragma unroll
        for (int mi = 0; mi < 4; ++mi) {
            int mrow = m0 + mi * 16 + quad * 4;
            #pragma unroll
            for (int r = 0; r < 4; ++r)
                out[(size_t)(mrow + r) * Ee + e] = acc[mi][ni][r] + be;
        }
    }
}

extern "C" void kernel_launch(void* const* d_in, const int* in_sizes, int n_in,
                              void* d_out, int out_size, void* d_ws, size_t ws_size,
                              hipStream_t stream) {
    const float* q      = (const float*)d_in[0];
    const float* k      = (const float*)d_in[1];
    const float* v      = (const float*)d_in[2];
    const float* qscale = (const float*)d_in[3];
    const float* kscale = (const float*)d_in[4];
    const float* projw  = (const float*)d_in[5];
    const float* projb  = (const float*)d_in[6];
    float* out = (float*)d_out;

    char* base = (char*)d_ws;
    float* ctab  = (float*)(base);
    float* stab  = (float*)(base + 131072);
    float* sctab = (float*)(base + 262144);
    unsigned short* qn   = (unsigned short*)(base + 393216);
    unsigned short* kn   = (unsigned short*)(base + 12976128);
    unsigned short* vt   = (unsigned short*)(base + 25559040);
    unsigned short* yatt = (unsigned short*)(base + 38141952);
    unsigned short* wb   = (unsigned short*)(base + 50724864);

    misc_kernel<<<128 + (Ee * Ee / 4) / 256, 256, 0, stream>>>(
        ctab, stab, sctab, projw, wb);
    prep_kernel<<<(Bb * Hh * Nn) / 4, 256, 0, stream>>>(
        q, k, qscale, kscale, ctab, stab, sctab, qn, kn);
    vt_kernel<<<Bb * Hh * 32, 256, 0, stream>>>(v, vt);

    dim3 agrid(Bb * Hh, NTQ / 2);                        // (48, 16): bh -> XCD
    attn_kernel<<<agrid, 256, 0, stream>>>(qn, kn, vt, yatt);

    dim3 ggrid(Ee / 128, (Bb * Nn) / 64);                // (6, 128)
    proj_kernel<<<ggrid, 256, 0, stream>>>(yatt, wb, projb, out);
}